// Round 2
// baseline (3985.834 us; speedup 1.0000x reference)
//
#include <hip/hip_runtime.h>
#include <hip/hip_fp16.h>

#define B_   32
#define S_   256
#define EMB_ 512
#define H_   1024
#define G4_  4096
#define NL_  5

// ---------------------------------------------------------------------------
// K0: transpose U [1024][4096] -> Ut [4096][1024] so the step kernel can
// stage each gate column as a contiguous 4KB row.
// grid (4096/32, 1024/32), block 256
__global__ __launch_bounds__(256) void k_transpose(const float* __restrict__ U,
                                                   float* __restrict__ Ut) {
  __shared__ float tile[32][33];
  int c0 = blockIdx.x * 32, k0 = blockIdx.y * 32;
  int tx = threadIdx.x & 31, ty = threadIdx.x >> 5;
#pragma unroll
  for (int i = 0; i < 4; ++i)
    tile[ty + 8 * i][tx] = U[(size_t)(k0 + ty + 8 * i) * G4_ + c0 + tx];
  __syncthreads();
#pragma unroll
  for (int i = 0; i < 4; ++i)
    Ut[(size_t)(c0 + ty + 8 * i) * H_ + k0 + tx] = tile[tx][ty + 8 * i];
}

// ---------------------------------------------------------------------------
// K1: xz[s][col][b] = sum_e emb[tok[b][s]][e] * W[e][col] + bias[col], fp16 out.
// grid (4096/128, 256), block 256. Block tile: 32 b x 128 cols, K-chunks of 32.
__global__ __launch_bounds__(256) void k_xw(const int* __restrict__ tokens,
                                            const float* __restrict__ emb,
                                            const float* __restrict__ W,
                                            const float* __restrict__ bias,
                                            unsigned short* __restrict__ xz) {
  __shared__ int tok_s[32];
  __shared__ float A_lds[32 * 36];              // [kk][b], stride 36
  __shared__ float B_lds[32 * 128];             // [kk][c]
  __shared__ unsigned short zout[128 * 40];     // [c][b] staging for coalesced store

  int s = blockIdx.y;
  int c0 = blockIdx.x * 128;
  int tid = threadIdx.x;
  if (tid < 32) tok_s[tid] = tokens[tid * S_ + s];

  int tc = tid & 31, tb = tid >> 5;
  int ar = tid >> 3, ap = tid & 7;   // A gather: batch row ar, float4 slot ap

  float acc[4][4];
#pragma unroll
  for (int i = 0; i < 4; ++i)
#pragma unroll
    for (int j = 0; j < 4; ++j) acc[i][j] = 0.f;

  for (int kb = 0; kb < 16; ++kb) {
    int k0 = kb * 32;
    __syncthreads();
    // A: emb[tok[ar]][k0 + 4*ap .. +3] -> A_lds[4*ap+j][ar]
    {
      const float4 av = *(const float4*)(emb + (size_t)tok_s[ar] * EMB_ + k0 + ap * 4);
      A_lds[(ap * 4 + 0) * 36 + ar] = av.x;
      A_lds[(ap * 4 + 1) * 36 + ar] = av.y;
      A_lds[(ap * 4 + 2) * 36 + ar] = av.z;
      A_lds[(ap * 4 + 3) * 36 + ar] = av.w;
    }
    // B: W[k0+kk][c0 + 4*tc ..]
#pragma unroll
    for (int i = 0; i < 4; ++i) {
      int kk = tb + 8 * i;
      float4 bv = *(const float4*)(W + (size_t)(k0 + kk) * G4_ + c0 + 4 * tc);
      *(float4*)(&B_lds[kk * 128 + 4 * tc]) = bv;
    }
    __syncthreads();
#pragma unroll
    for (int kk = 0; kk < 32; ++kk) {
      float a0 = A_lds[kk * 36 + tb];
      float a1 = A_lds[kk * 36 + tb + 8];
      float a2 = A_lds[kk * 36 + tb + 16];
      float a3 = A_lds[kk * 36 + tb + 24];
      float b0 = B_lds[kk * 128 + tc];
      float b1 = B_lds[kk * 128 + tc + 32];
      float b2 = B_lds[kk * 128 + tc + 64];
      float b3 = B_lds[kk * 128 + tc + 96];
      acc[0][0] += a0 * b0; acc[0][1] += a1 * b0; acc[0][2] += a2 * b0; acc[0][3] += a3 * b0;
      acc[1][0] += a0 * b1; acc[1][1] += a1 * b1; acc[1][2] += a2 * b1; acc[1][3] += a3 * b1;
      acc[2][0] += a0 * b2; acc[2][1] += a1 * b2; acc[2][2] += a2 * b2; acc[2][3] += a3 * b2;
      acc[3][0] += a0 * b3; acc[3][1] += a1 * b3; acc[3][2] += a2 * b3; acc[3][3] += a3 * b3;
    }
  }
  __syncthreads();
#pragma unroll
  for (int qc = 0; qc < 4; ++qc) {
    float bv = bias[c0 + tc + 32 * qc];
#pragma unroll
    for (int qb = 0; qb < 4; ++qb) {
      float v = acc[qc][qb] + bv;
      zout[(tc + 32 * qc) * 40 + tb + 8 * qb] = __half_as_ushort(__float2half_rn(v));
    }
  }
  __syncthreads();
  // coalesced store: thread -> (cc = tid>>1, 16-ushort half = TWO uint4s)
  {
    int cc = tid >> 1, hh = (tid & 1) * 16;
    uint4 v0 = *(const uint4*)(&zout[cc * 40 + hh]);
    uint4 v1 = *(const uint4*)(&zout[cc * 40 + hh + 8]);
    unsigned short* dst = xz + ((size_t)s * G4_ + c0 + cc) * 32 + hh;
    *(uint4*)(dst) = v0;
    *(uint4*)(dst + 8) = v1;
  }
}

// ---------------------------------------------------------------------------
// K2: one LSTM step. grid 256 (block owns hidden units u0..u0+3 = 16 U cols),
// block 512. z = xz[t] + h_in @ U ; gates ; c,h update. h layout [k][b] fp32.
__global__ __launch_bounds__(512) void k_step(const float* __restrict__ Ut,
                                              const unsigned short* __restrict__ xz,
                                              const float* __restrict__ h_in,
                                              float* __restrict__ h_out,
                                              float* __restrict__ c_buf,
                                              int t) {
  __shared__ float h_lds[256 * 34];        // [klocal][b], stride 34 (2-way only)
  __shared__ float U_lds[16 * 260];        // [c][klocal]
  __shared__ float red_s[32 * 16 * 34];    // [kseg][c][b]
  __shared__ float zg[16 * 33];            // [c][b]

  int tid = threadIdx.x;
  int u0 = blockIdx.x * 4;

  float acc[32];
#pragma unroll
  for (int i = 0; i < 32; ++i) acc[i] = 0.f;

  if (t > 0) {
    int kseg = tid >> 4, cl = tid & 15;              // 32 ksegs x 16 cols
    int srow = tid >> 1, shalf = (tid & 1) * 16;     // h staging
    int uc = tid >> 5, upart = tid & 31;             // U staging
    int ugcol = (uc & 3) * H_ + u0 + (uc >> 2);      // c = j*4+g -> col g*1024+u0+j
    for (int ch = 0; ch < 4; ++ch) {
      {
        const float* src = h_in + ch * 8192 + srow * 32 + shalf;
        float* dst = h_lds + srow * 34 + shalf;
#pragma unroll
        for (int j = 0; j < 8; ++j)
          *(float2*)(dst + 2 * j) = *(const float2*)(src + 2 * j);
      }
      {
        const float* usrc = Ut + (size_t)ugcol * H_ + ch * 256 + upart * 8;
        float* udst = U_lds + uc * 260 + upart * 8;
        *(float4*)(udst) = *(const float4*)(usrc);
        *(float4*)(udst + 4) = *(const float4*)(usrc + 4);
      }
      __syncthreads();
#pragma unroll
      for (int kk = 0; kk < 8; ++kk) {
        int kl = kseg * 8 + kk;
        float uval = U_lds[cl * 260 + kl];
        const float2* h2 = (const float2*)(h_lds + kl * 34);
#pragma unroll
        for (int bq = 0; bq < 16; ++bq) {
          float2 hv = h2[bq];
          acc[2 * bq]     += hv.x * uval;
          acc[2 * bq + 1] += hv.y * uval;
        }
      }
      __syncthreads();
    }
  }
  // write partials red[kseg][cl][b]
  {
    int kseg = tid >> 4, cl = tid & 15;
    float* r = red_s + kseg * 544 + cl * 34;
#pragma unroll
    for (int bq = 0; bq < 16; ++bq)
      *(float2*)(r + 2 * bq) = make_float2(acc[2 * bq], acc[2 * bq + 1]);
  }
  __syncthreads();
  // reduce over 32 ksegs + add xz; one z per thread
  {
    int b = tid & 31, c = tid >> 5;
    float z = 0.f;
#pragma unroll
    for (int ks = 0; ks < 32; ++ks) z += red_s[ks * 544 + c * 34 + b];
    int gcol = (c & 3) * H_ + u0 + (c >> 2);
    z += __half2float(__ushort_as_half(xz[((size_t)t * G4_ + gcol) * 32 + b]));
    zg[c * 33 + b] = z;
  }
  __syncthreads();
  if (tid < 128) {  // 32 b x 4 units
    int b = tid & 31, j = tid >> 5;
    float zi = zg[(4 * j + 0) * 33 + b];
    float zf = zg[(4 * j + 1) * 33 + b];
    float zc = zg[(4 * j + 2) * 33 + b];
    float zo = zg[(4 * j + 3) * 33 + b];
    float ig = 1.f / (1.f + __expf(-zi));
    float fg = 1.f / (1.f + __expf(-zf));
    float gg = tanhf(zc);
    float og = 1.f / (1.f + __expf(-zo));
    int idx = (u0 + j) * 32 + b;
    float cold = (t > 0) ? c_buf[idx] : 0.f;
    float cnew = fg * cold + ig * gg;
    c_buf[idx] = cnew;
    h_out[idx] = og * tanhf(cnew);
  }
}

// ---------------------------------------------------------------------------
// K3: logits[b][l] = sum_k h[k][b] * Wd[k][l] + bd[l]. grid 5, block 256.
__global__ __launch_bounds__(256) void k_head(const float* __restrict__ h,
                                              const float* __restrict__ Wd,
                                              const float* __restrict__ bd,
                                              float* __restrict__ out) {
  __shared__ float red[8][33];
  int l = blockIdx.x;
  int b = threadIdx.x & 31, ks = threadIdx.x >> 5;
  float acc = 0.f;
  for (int k = ks * 128; k < ks * 128 + 128; ++k)
    acc += h[k * 32 + b] * Wd[k * NL_ + l];
  red[ks][b] = acc;
  __syncthreads();
  if (threadIdx.x < 32) {
    float ssum = bd[l];
#pragma unroll
    for (int i = 0; i < 8; ++i) ssum += red[i][b];
    out[b * NL_ + l] = ssum;
  }
}

// ---------------------------------------------------------------------------
extern "C" void kernel_launch(void* const* d_in, const int* in_sizes, int n_in,
                              void* d_out, int out_size, void* d_ws, size_t ws_size,
                              hipStream_t stream) {
  const int* tokens  = (const int*)d_in[0];
  const float* emb   = (const float*)d_in[1];
  const float* W     = (const float*)d_in[2];
  const float* U     = (const float*)d_in[3];
  const float* bias  = (const float*)d_in[4];
  const float* Wd    = (const float*)d_in[5];
  const float* bd    = (const float*)d_in[6];
  float* out = (float*)d_out;

  char* ws = (char*)d_ws;
  // layout: Ut fp32 [4096][1024] | xz fp16 [256][4096][32] | h fp32 2x[1024][32] | c fp32 [1024][32]
  float* Ut            = (float*)ws;                          // 16,777,216 B
  unsigned short* xz   = (unsigned short*)(ws + 16777216);    // 67,108,864 B
  float* hbuf          = (float*)(ws + 83886080);             //    262,144 B
  float* cbuf          = (float*)(ws + 84148224);             //    131,072 B
  // total 84,279,296 B required from d_ws

  k_transpose<<<dim3(128, 32), 256, 0, stream>>>(U, Ut);
  k_xw<<<dim3(32, 256), 256, 0, stream>>>(tokens, emb, W, bias, xz);
  for (int t = 0; t < S_; ++t) {
    float* ho = hbuf + (t & 1) * 32768;
    const float* hi = hbuf + ((t & 1) ^ 1) * 32768;
    k_step<<<256, 512, 0, stream>>>(Ut, xz, hi, ho, cbuf, t);
  }
  k_head<<<NL_, 256, 0, stream>>>(hbuf + 32768, Wd, bd, out);
}

// Round 3
// 2602.890 us; speedup vs baseline: 1.5313x; 1.5313x over previous
//
#include <hip/hip_runtime.h>
#include <hip/hip_fp16.h>

#define B_   32
#define S_   256
#define EMB_ 512
#define H_   1024
#define G4_  4096
#define NL_  5

typedef short bf16x8 __attribute__((ext_vector_type(8)));
typedef float f32x4 __attribute__((ext_vector_type(4)));

__device__ inline unsigned short f2bf(float x) {
  unsigned u = __float_as_uint(x);
  return (unsigned short)((u + 0x7FFF + ((u >> 16) & 1)) >> 16);
}
__device__ inline float bf2f(unsigned short b) {
  return __uint_as_float(((unsigned)b) << 16);
}

// ---------------------------------------------------------------------------
// K0: transpose U [1024][4096] -> Ut [4096][1024] (coalesced both sides).
__global__ __launch_bounds__(256) void k_transpose(const float* __restrict__ U,
                                                   float* __restrict__ Ut) {
  __shared__ float tile[32][33];
  int c0 = blockIdx.x * 32, k0 = blockIdx.y * 32;
  int tx = threadIdx.x & 31, ty = threadIdx.x >> 5;
#pragma unroll
  for (int i = 0; i < 4; ++i)
    tile[ty + 8 * i][tx] = U[(size_t)(k0 + ty + 8 * i) * G4_ + c0 + tx];
  __syncthreads();
#pragma unroll
  for (int i = 0; i < 4; ++i)
    Ut[(size_t)(c0 + ty + 8 * i) * H_ + k0 + tx] = tile[tx][ty + 8 * i];
}

// ---------------------------------------------------------------------------
// K0b: build MFMA-ready B-fragments of U, split bf16 hi/lo.
// Slot (bx, w, s, plane, lane l, j): value U[k][gcol],
//   k = w*256 + s*32 + (l>>4)*8 + j,  n = l&15, gcol = (n&3)*1024 + bx*4 + (n>>2)
// Layout: Ubf[((bx*4+w)*8+s)*128 + plane*64 + l] as bf16x8. 524288 threads.
__global__ __launch_bounds__(256) void k_prep(const float* __restrict__ Ut,
                                              bf16x8* __restrict__ Ubf) {
  int gid = blockIdx.x * 256 + threadIdx.x;
  int l = gid & 63;
  int bxws = gid >> 6;               // (bx*4+w)*8+s
  int n = l & 15, kgrp = l >> 4;
  int s = bxws & 7, bw = bxws >> 3;  // bw = bx*4+w
  int w = bw & 3, bx = bw >> 2;
  int g = n & 3, ju = n >> 2;
  int gcol = g * 1024 + bx * 4 + ju;
  int kbase = w * 256 + s * 32 + kgrp * 8;
  const float4* f = (const float4*)(Ut + (size_t)gcol * H_ + kbase);
  float4 f0 = f[0], f1 = f[1];
  float v[8] = {f0.x, f0.y, f0.z, f0.w, f1.x, f1.y, f1.z, f1.w};
  bf16x8 vh, vl;
#pragma unroll
  for (int j = 0; j < 8; ++j) {
    unsigned short hi = f2bf(v[j]);
    vh[j] = (short)hi;
    vl[j] = (short)f2bf(v[j] - bf2f(hi));
  }
  Ubf[(size_t)bxws * 128 + l] = vh;
  Ubf[(size_t)bxws * 128 + 64 + l] = vl;
}

// ---------------------------------------------------------------------------
// K1: xz[s][col][b] = sum_e emb[tok[b][s]][e] * W[e][col] + bias[col], fp16 out.
// (unchanged from round 2 — known good)
__global__ __launch_bounds__(256) void k_xw(const int* __restrict__ tokens,
                                            const float* __restrict__ emb,
                                            const float* __restrict__ W,
                                            const float* __restrict__ bias,
                                            unsigned short* __restrict__ xz) {
  __shared__ int tok_s[32];
  __shared__ float A_lds[32 * 36];
  __shared__ float B_lds[32 * 128];
  __shared__ unsigned short zout[128 * 40];

  int s = blockIdx.y;
  int c0 = blockIdx.x * 128;
  int tid = threadIdx.x;
  if (tid < 32) tok_s[tid] = tokens[tid * S_ + s];

  int tc = tid & 31, tb = tid >> 5;
  int ar = tid >> 3, ap = tid & 7;

  float acc[4][4];
#pragma unroll
  for (int i = 0; i < 4; ++i)
#pragma unroll
    for (int j = 0; j < 4; ++j) acc[i][j] = 0.f;

  for (int kb = 0; kb < 16; ++kb) {
    int k0 = kb * 32;
    __syncthreads();
    {
      const float4 av = *(const float4*)(emb + (size_t)tok_s[ar] * EMB_ + k0 + ap * 4);
      A_lds[(ap * 4 + 0) * 36 + ar] = av.x;
      A_lds[(ap * 4 + 1) * 36 + ar] = av.y;
      A_lds[(ap * 4 + 2) * 36 + ar] = av.z;
      A_lds[(ap * 4 + 3) * 36 + ar] = av.w;
    }
#pragma unroll
    for (int i = 0; i < 4; ++i) {
      int kk = tb + 8 * i;
      float4 bv = *(const float4*)(W + (size_t)(k0 + kk) * G4_ + c0 + 4 * tc);
      *(float4*)(&B_lds[kk * 128 + 4 * tc]) = bv;
    }
    __syncthreads();
#pragma unroll
    for (int kk = 0; kk < 32; ++kk) {
      float a0 = A_lds[kk * 36 + tb];
      float a1 = A_lds[kk * 36 + tb + 8];
      float a2 = A_lds[kk * 36 + tb + 16];
      float a3 = A_lds[kk * 36 + tb + 24];
      float b0 = B_lds[kk * 128 + tc];
      float b1 = B_lds[kk * 128 + tc + 32];
      float b2 = B_lds[kk * 128 + tc + 64];
      float b3 = B_lds[kk * 128 + tc + 96];
      acc[0][0] += a0 * b0; acc[0][1] += a1 * b0; acc[0][2] += a2 * b0; acc[0][3] += a3 * b0;
      acc[1][0] += a0 * b1; acc[1][1] += a1 * b1; acc[1][2] += a2 * b1; acc[1][3] += a3 * b1;
      acc[2][0] += a0 * b2; acc[2][1] += a1 * b2; acc[2][2] += a2 * b2; acc[2][3] += a3 * b2;
      acc[3][0] += a0 * b3; acc[3][1] += a1 * b3; acc[3][2] += a2 * b3; acc[3][3] += a3 * b3;
    }
  }
  __syncthreads();
#pragma unroll
  for (int qc = 0; qc < 4; ++qc) {
    float bv = bias[c0 + tc + 32 * qc];
#pragma unroll
    for (int qb = 0; qb < 4; ++qb) {
      float v = acc[qc][qb] + bv;
      zout[(tc + 32 * qc) * 40 + tb + 8 * qb] = __half_as_ushort(__float2half_rn(v));
    }
  }
  __syncthreads();
  {
    int cc = tid >> 1, hh = (tid & 1) * 16;
    uint4 v0 = *(const uint4*)(&zout[cc * 40 + hh]);
    uint4 v1 = *(const uint4*)(&zout[cc * 40 + hh + 8]);
    unsigned short* dst = xz + ((size_t)s * G4_ + c0 + cc) * 32 + hh;
    *(uint4*)(dst) = v0;
    *(uint4*)(dst + 8) = v1;
  }
}

// ---------------------------------------------------------------------------
// K2: one LSTM step, split-bf16 MFMA. grid 256 (block = 4 hidden units = 16
// gate cols), block 256 (4 waves, k-split 256 each).
// z[b][n] = sum_k h[b][k] * U[k][gcol(n)] + xz  ->  gates -> c,h update.
// h stored [32][1024] bf16 hi/lo planes (A-frags = contiguous 16B loads).
__global__ __launch_bounds__(256) void k_step2(
    const bf16x8* __restrict__ Ubf,
    const unsigned short* __restrict__ xz,
    const unsigned short* __restrict__ h_hi_in,
    const unsigned short* __restrict__ h_lo_in,
    unsigned short* __restrict__ h_hi_out,
    unsigned short* __restrict__ h_lo_out,
    float* __restrict__ c_buf,
    int t) {
  __shared__ float red[2048];     // [w][m][row*16+col]
  __shared__ float zg[32 * 17];   // [b][n]

  int tid = threadIdx.x;
  int bx = blockIdx.x;
  int u0 = bx * 4;
  int l = tid & 63, w = tid >> 6;
  int bL = l & 15, kg = l >> 4;

  if (t > 0) {
    f32x4 c0 = {0.f, 0.f, 0.f, 0.f}, c1 = {0.f, 0.f, 0.f, 0.f};
    const bf16x8* Hh = (const bf16x8*)h_hi_in;   // [32][128] bf16x8
    const bf16x8* Hl = (const bf16x8*)h_lo_in;
    size_t ubase = (size_t)((bx * 4 + w) * 8) * 128;
#pragma unroll
    for (int s = 0; s < 8; ++s) {
      int kidx = w * 32 + s * 4 + kg;            // k offset in 8-elem units
      bf16x8 bh  = Ubf[ubase + s * 128 + l];
      bf16x8 blo = Ubf[ubase + s * 128 + 64 + l];
      bf16x8 a0h = Hh[bL * 128 + kidx];
      bf16x8 a0l = Hl[bL * 128 + kidx];
      bf16x8 a1h = Hh[(16 + bL) * 128 + kidx];
      bf16x8 a1l = Hl[(16 + bL) * 128 + kidx];
      c0 = __builtin_amdgcn_mfma_f32_16x16x32_bf16(a0h, bh,  c0, 0, 0, 0);
      c1 = __builtin_amdgcn_mfma_f32_16x16x32_bf16(a1h, bh,  c1, 0, 0, 0);
      c0 = __builtin_amdgcn_mfma_f32_16x16x32_bf16(a0l, bh,  c0, 0, 0, 0);
      c1 = __builtin_amdgcn_mfma_f32_16x16x32_bf16(a1l, bh,  c1, 0, 0, 0);
      c0 = __builtin_amdgcn_mfma_f32_16x16x32_bf16(a0h, blo, c0, 0, 0, 0);
      c1 = __builtin_amdgcn_mfma_f32_16x16x32_bf16(a1h, blo, c1, 0, 0, 0);
    }
#pragma unroll
    for (int r = 0; r < 4; ++r) {
      red[(w * 2 + 0) * 256 + (kg * 4 + r) * 16 + bL] = c0[r];
      red[(w * 2 + 1) * 256 + (kg * 4 + r) * 16 + bL] = c1[r];
    }
  }
  __syncthreads();
  // two z per thread: e = m*256 + tid, pos = tid -> row = pos>>4, n = pos&15
#pragma unroll
  for (int m = 0; m < 2; ++m) {
    int row = tid >> 4, n = tid & 15;
    int b = m * 16 + row;
    float z = 0.f;
    if (t > 0)
      z = red[(0 * 2 + m) * 256 + tid] + red[(1 * 2 + m) * 256 + tid] +
          red[(2 * 2 + m) * 256 + tid] + red[(3 * 2 + m) * 256 + tid];
    int gcol = (n & 3) * 1024 + u0 + (n >> 2);
    z += __half2float(__ushort_as_half(xz[((size_t)t * G4_ + gcol) * 32 + b]));
    zg[b * 17 + n] = z;
  }
  __syncthreads();
  if (tid < 128) {
    int b = tid & 31, j = tid >> 5;
    float zi = zg[b * 17 + j * 4 + 0];
    float zf = zg[b * 17 + j * 4 + 1];
    float zc = zg[b * 17 + j * 4 + 2];
    float zo = zg[b * 17 + j * 4 + 3];
    float ig = 1.f / (1.f + __expf(-zi));
    float fg = 1.f / (1.f + __expf(-zf));
    float gg = tanhf(zc);
    float og = 1.f / (1.f + __expf(-zo));
    int ci = (u0 + j) * 32 + b;
    float cold = (t > 0) ? c_buf[ci] : 0.f;
    float cn = fg * cold + ig * gg;
    c_buf[ci] = cn;
    float hv = og * tanhf(cn);
    unsigned short hh = f2bf(hv);
    unsigned short hl = f2bf(hv - bf2f(hh));
    h_hi_out[b * H_ + u0 + j] = hh;
    h_lo_out[b * H_ + u0 + j] = hl;
  }
}

// ---------------------------------------------------------------------------
// K3: logits[b][l] = sum_k (hi+lo)[b][k] * Wd[k][l] + bd[l]. grid 5, block 256.
__global__ __launch_bounds__(256) void k_head2(const unsigned short* __restrict__ hh,
                                               const unsigned short* __restrict__ hl,
                                               const float* __restrict__ Wd,
                                               const float* __restrict__ bd,
                                               float* __restrict__ out) {
  __shared__ float red[32 * 9];
  int lbl = blockIdx.x;
  int tid = threadIdx.x;
  int b = tid >> 3, ks = tid & 7;
  float acc = 0.f;
  for (int k = ks * 128; k < ks * 128 + 128; ++k) {
    float hv = bf2f(hh[b * H_ + k]) + bf2f(hl[b * H_ + k]);
    acc += hv * Wd[k * NL_ + lbl];
  }
  red[b * 9 + ks] = acc;
  __syncthreads();
  if (tid < 32) {
    float s = bd[lbl];
#pragma unroll
    for (int i = 0; i < 8; ++i) s += red[tid * 9 + i];
    out[tid * NL_ + lbl] = s;
  }
}

// ---------------------------------------------------------------------------
extern "C" void kernel_launch(void* const* d_in, const int* in_sizes, int n_in,
                              void* d_out, int out_size, void* d_ws, size_t ws_size,
                              hipStream_t stream) {
  const int* tokens  = (const int*)d_in[0];
  const float* emb   = (const float*)d_in[1];
  const float* W     = (const float*)d_in[2];
  const float* U     = (const float*)d_in[3];
  const float* bias  = (const float*)d_in[4];
  const float* Wd    = (const float*)d_in[5];
  const float* bd    = (const float*)d_in[6];
  float* out = (float*)d_out;

  char* ws = (char*)d_ws;
  // Overlaid layout (84,279,296 B total — same footprint as round 2):
  //   Ut fp32 [4096][1024]  @ 0          (16 MB, transient — dead after k_prep)
  //   xz fp16 [256][4096][32] @ 0        (64 MB, written by k_xw AFTER k_prep)
  //   Ubf bf16 frags        @ 67,108,864 (16 MB)
  //   h planes (hi0,lo0,hi1,lo1 bf16 [32][1024]) @ 83,886,080 (4 x 64 KB)
  //   c fp32 [1024][32]     @ 84,148,224 (128 KB)
  float* Ut          = (float*)ws;
  unsigned short* xz = (unsigned short*)ws;
  bf16x8* Ubf        = (bf16x8*)(ws + 67108864);
  unsigned short* h00 = (unsigned short*)(ws + 83886080);            // buf0 hi
  unsigned short* h01 = (unsigned short*)(ws + 83886080 + 65536);    // buf0 lo
  unsigned short* h10 = (unsigned short*)(ws + 83886080 + 131072);   // buf1 hi
  unsigned short* h11 = (unsigned short*)(ws + 83886080 + 196608);   // buf1 lo
  float* cbuf        = (float*)(ws + 84148224);

  k_transpose<<<dim3(128, 32), 256, 0, stream>>>(U, Ut);
  k_prep<<<2048, 256, 0, stream>>>(Ut, Ubf);
  k_xw<<<dim3(32, 256), 256, 0, stream>>>(tokens, emb, W, bias, xz);  // clobbers Ut (dead)

  for (int t = 0; t < S_; ++t) {
    const unsigned short* hi_in = (t & 1) ? h10 : h00;
    const unsigned short* lo_in = (t & 1) ? h11 : h01;
    unsigned short* hi_out = (t & 1) ? h00 : h10;
    unsigned short* lo_out = (t & 1) ? h01 : h11;
    k_step2<<<256, 256, 0, stream>>>(Ubf, xz, hi_in, lo_in, hi_out, lo_out, cbuf, t);
  }
  // t=255 wrote buf0 (h00/h01)
  k_head2<<<NL_, 256, 0, stream>>>(h00, h01, Wd, bd, out);
}